// Round 24
// baseline (94.608 us; speedup 1.0000x reference)
//
#include <hip/hip_runtime.h>
#include <hip/hip_bf16.h>
#include <math.h>

// Problem constants
#define NB 2
#define NS 2048
#define ND 1024
#define NH 16
#define HD 64
#define BS (NB*NS)     // 4096 tokens
#define D3 (3*ND)      // 3072
#define NT (NS/64)     // 32 q-tiles of 64

typedef __bf16 bf16;
typedef __bf16 bf16x4 __attribute__((ext_vector_type(4)));
typedef __bf16 bf16x8 __attribute__((ext_vector_type(8)));
typedef float f32x4 __attribute__((ext_vector_type(4)));

#define MFMA16(a,b,c) __builtin_amdgcn_mfma_f32_16x16x32_bf16(a,b,c,0,0,0)

static __device__ inline f32x4 zero4() { f32x4 z; z[0]=0.f; z[1]=0.f; z[2]=0.f; z[3]=0.f; return z; }

// global -> LDS direct copy, 16B per lane; lds base must be wave-uniform.
__device__ __forceinline__ void gload_lds16(const bf16* g, bf16* l) {
    __builtin_amdgcn_global_load_lds(
        (__attribute__((address_space(1))) unsigned int*)g,
        (__attribute__((address_space(3))) unsigned int*)l, 16, 0, 0);
}

// ---------------- prep: f32->bf16 for x/w_in/w_out + RoPE float2 table, one launch ----------------
#define CVT1 (BS*ND/8)          // 524288
#define CVT2 (D3*ND/8)          // 393216
#define CVT3 (ND*ND/8)          // 131072
#define CVTN (CVT1+CVT2+CVT3)   // 1048576
__global__ __launch_bounds__(256) void prep(
    const float* __restrict__ x, const float* __restrict__ w_in, const float* __restrict__ w_out,
    bf16* __restrict__ xb, bf16* __restrict__ winb, bf16* __restrict__ woutb,
    float2* __restrict__ csT)
{
    int i = blockIdx.x * 256 + threadIdx.x;
    if (i < CVTN) {
        const float* in; bf16* out; int j;
        if (i < CVT1)            { in = x;     out = xb;    j = i; }
        else if (i < CVT1+CVT2)  { in = w_in;  out = winb;  j = i - CVT1; }
        else                     { in = w_out; out = woutb; j = i - CVT1 - CVT2; }
        const float4* p = (const float4*)in;
        float4 a = p[j*2], b = p[j*2+1];
        bf16x8 o;
        o[0]=(bf16)a.x; o[1]=(bf16)a.y; o[2]=(bf16)a.z; o[3]=(bf16)a.w;
        o[4]=(bf16)b.x; o[5]=(bf16)b.y; o[6]=(bf16)b.z; o[7]=(bf16)b.w;
        ((bf16x8*)out)[j] = o;
    } else {
        int k = i - CVTN;                      // [0, NS*32)
        int s = k >> 5, j = k & 31;
        float inv = __expf(-(float)j * (9.210340372f * 0.03125f));  // 10000^(-j/32)
        float ang = (float)s * inv;
        csT[k] = make_float2(cosf(ang), sinf(ang));
    }
}

// ---------------- QKV GEMM: 128x192 tile, 4 waves, 2 blocks/CU, 100% fill (r19/r21) ----------
__global__ __launch_bounds__(256, 2) void gemm_qkv(
    const bf16* __restrict__ A, const bf16* __restrict__ Bm,
    bf16* __restrict__ Qb, bf16* __restrict__ Kb, bf16* __restrict__ Vt,
    const float2* __restrict__ csT)
{
    __shared__ bf16 As[2][128*64];     // 32KB
    __shared__ bf16 Bs[2][192*64];     // 48KB
    int t = threadIdx.x;
    int lane = t & 63, w = t >> 6;      // 4 waves
    int lr = lane & 15, lg = lane >> 4;
    int m0 = blockIdx.y * 128, n0 = blockIdx.x * 192;

    int srow8 = lane >> 3;              // 0..7
    int schunk = (lane & 7) ^ srow8;    // pre-swizzled source chunk (rule 21)
    const bf16* gA = A  + (size_t)(m0 + srow8)*ND + schunk*8;
    const bf16* gB = Bm + (size_t)(n0 + srow8)*ND + schunk*8;

    auto stage = [&](int kt) {
        int buf = kt & 1, k0 = kt*64;
        #pragma unroll
        for (int i=0;i<4;i++) {
            int r0 = w*32 + i*8;                       // A rows, 32/wave
            gload_lds16(gA + (size_t)r0*ND + k0, &As[buf][r0*64]);
        }
        #pragma unroll
        for (int i=0;i<6;i++) {
            int r0 = w*48 + i*8;                       // B rows, 48/wave
            gload_lds16(gB + (size_t)r0*ND + k0, &Bs[buf][r0*64]);
        }
    };

    f32x4 acc[2][12];
    #pragma unroll
    for (int mm=0;mm<2;mm++)
        #pragma unroll
        for (int n=0;n<12;n++) acc[mm][n] = zero4();

    bf16x8 af[2][2], bfr[4][2];

    stage(0); stage(1);                 // 20 loads/wave outstanding

    for (int kt = 0; kt < 16; kt++) {
        int cur = kt & 1;
        const bf16* as = &As[cur][0];
        const bf16* bs = &Bs[cur][0];
        if (kt < 15) asm volatile("s_waitcnt vmcnt(10)" ::: "memory");
        else         asm volatile("s_waitcnt vmcnt(0)" ::: "memory");
        __builtin_amdgcn_s_barrier();
        __builtin_amdgcn_sched_barrier(0);

        // A fragments once per tile
        #pragma unroll
        for (int mm=0;mm<2;mm++) {
            int row = w*32 + mm*16 + lr;
            af[mm][0] = *(const bf16x8*)&as[row*64 + ((lg     ^ (row&7))*8)];
            af[mm][1] = *(const bf16x8*)&as[row*64 + (((4+lg) ^ (row&7))*8)];
        }

        // 3 groups of 4 B-fragments; group 2 releases the buffer + stages kt+2
        #pragma unroll
        for (int g=0; g<3; g++) {
            #pragma unroll
            for (int nn=0;nn<4;nn++) {
                int row = g*64 + nn*16 + lr;
                bfr[nn][0] = *(const bf16x8*)&bs[row*64 + ((lg     ^ (row&7))*8)];
                bfr[nn][1] = *(const bf16x8*)&bs[row*64 + (((4+lg) ^ (row&7))*8)];
            }
            asm volatile("s_waitcnt lgkmcnt(0)" ::: "memory");
            __builtin_amdgcn_sched_barrier(0);
            if (g == 2) {                              // all LDS reads of buf cur done
                __builtin_amdgcn_s_barrier();
                __builtin_amdgcn_sched_barrier(0);
                if (kt + 2 < 16) stage(kt + 2);        // refill buf cur for tile kt+2
            }
            __builtin_amdgcn_s_setprio(1);
            #pragma unroll
            for (int ks=0;ks<2;ks++)
                #pragma unroll
                for (int mm=0;mm<2;mm++)
                    #pragma unroll
                    for (int nn=0;nn<4;nn++)
                        acc[mm][g*4+nn] = MFMA16(af[mm][ks], bfr[nn][ks], acc[mm][g*4+nn]);
            __builtin_amdgcn_s_setprio(0);
        }
    }

    // ---- epilogue: per-64-col-group which; fused RoPE / V^T scatter ----
    const float qs = 0.125f * 1.44269504f;   // fold softmax scale + log2(e) into Q
    #pragma unroll
    for (int a=0;a<3;a++) {
        int colbase = n0 + a*64;
        int which = colbase >> 10;           // uniform per group
        if (which == 2) {
            #pragma unroll
            for (int p=0;p<4;p++)
                #pragma unroll
                for (int mm=0;mm<2;mm++) {
                    int gcol = colbase + p*16 + lr;
                    int h = (gcol & 1023) >> 6, d = gcol & 63;
                    int grow = m0 + w*32 + mm*16 + lg*4;
                    int b = grow >> 11, s0 = grow & (NS-1);
                    int shi = s0 & ~63, j = s0 & 63;
                    int kp = ((j>>5)&1)*32 + ((j>>2)&3)*8 + ((j>>4)&1)*4;
                    bf16x4 pv;
                    #pragma unroll
                    for (int r=0;r<4;r++) pv[r] = (bf16)acc[mm][a*4+p][r];
                    *(bf16x4*)&Vt[((size_t)((b*NH + h)*HD + d))*NS + shi + kp] = pv;
                }
        } else {
            bf16* dst = (which == 0) ? Qb : Kb;
            #pragma unroll
            for (int p=0;p<2;p++)
                #pragma unroll
                for (int mm=0;mm<2;mm++) {
                    int gcol = colbase + p*16 + lr;
                    int h = (gcol & 1023) >> 6, j = gcol & 63;   // j in [0,32)
                    int grow = m0 + w*32 + mm*16 + lg*4;
                    #pragma unroll
                    for (int r=0;r<4;r++) {
                        int gm = grow + r;
                        int b = gm >> 11, s = gm & (NS-1);
                        float2 cs = csT[(s<<5)+j];
                        float x1 = acc[mm][a*4+p][r], x2 = acc[mm][a*4+p+2][r];
                        float y1 = x1*cs.x - x2*cs.y;
                        float y2 = x2*cs.x + x1*cs.y;
                        if (which == 0) { y1 *= qs; y2 *= qs; }
                        size_t off = ((size_t)((b*NH + h)*NS + s))*HD;
                        dst[off + j]      = (bf16)y1;
                        dst[off + j + 32] = (bf16)y2;
                    }
                }
        }
    }
}

// ---------------- out-proj GEMM: 64x128 tile, 512 blocks = 2/CU (r23 overlap fix) ----------
__global__ __launch_bounds__(256, 2) void gemm_out(
    const bf16* __restrict__ A, const bf16* __restrict__ Bm,
    float* __restrict__ C, int M, int N, int K)
{
    __shared__ bf16 As[2][64*64];      // 16KB
    __shared__ bf16 Bs[2][128*64];     // 32KB
    int t = threadIdx.x;
    int lane = t & 63, w = t >> 6;
    int wr = w >> 1, wc = w & 1;       // 2x2 waves of 32x64
    int lr = lane & 15, lg = lane >> 4;
    int m0 = blockIdx.y * 64, n0 = blockIdx.x * 128;

    int srow = lane >> 3;                 // 0..7
    int schunk = (lane & 7) ^ srow;       // XOR-swizzled source chunk
    const bf16* gA = &A [(size_t)(m0 + srow)*K + schunk*8];
    const bf16* gB = &Bm[(size_t)(n0 + srow)*K + schunk*8];

    auto stage = [&](int kt) {
        int buf = kt & 1;
        int k0 = kt * 64;
        #pragma unroll
        for (int i=0;i<2;i++) {
            int r0 = w*16 + i*8;                       // A rows, 16/wave
            gload_lds16(gA + (size_t)r0*K + k0, &As[buf][r0*64]);
        }
        #pragma unroll
        for (int i=0;i<4;i++) {
            int r0 = w*32 + i*8;                       // B rows, 32/wave
            gload_lds16(gB + (size_t)r0*K + k0, &Bs[buf][r0*64]);
        }
    };

    f32x4 acc[2][4];
    for (int m=0;m<2;m++) for (int n=0;n<4;n++) acc[m][n] = zero4();

    int nt = K >> 6;
    stage(0);
    stage(1);                          // 12 loads/wave outstanding

    for (int kt = 0; kt < nt; kt++) {
        int cur = kt & 1;
        if (kt < nt-1) asm volatile("s_waitcnt vmcnt(6)" ::: "memory");
        else           asm volatile("s_waitcnt vmcnt(0)" ::: "memory");
        __builtin_amdgcn_s_barrier();
        __builtin_amdgcn_sched_barrier(0);

        bf16x8 af[2][2], bfr[2][4];
        #pragma unroll
        for (int ks=0;ks<2;ks++) {
            #pragma unroll
            for (int m=0;m<2;m++) {
                int row = wr*32 + m*16 + lr;
                af[ks][m] = *(const bf16x8*)&As[cur][row*64 + (((ks*4+lg) ^ (row&7))*8)];
            }
            #pragma unroll
            for (int n=0;n<4;n++) {
                int row = wc*64 + n*16 + lr;
                bfr[ks][n] = *(const bf16x8*)&Bs[cur][row*64 + (((ks*4+lg) ^ (row&7))*8)];
            }
        }
        asm volatile("s_waitcnt lgkmcnt(0)" ::: "memory");
        __builtin_amdgcn_sched_barrier(0);
        __builtin_amdgcn_s_barrier();
        __builtin_amdgcn_sched_barrier(0);

        if (kt + 2 < nt) stage(kt + 2);

        __builtin_amdgcn_s_setprio(1);
        #pragma unroll
        for (int ks=0;ks<2;ks++)
            #pragma unroll
            for (int m=0;m<2;m++)
                #pragma unroll
                for (int n=0;n<4;n++)
                    acc[m][n] = MFMA16(af[ks][m], bfr[ks][n], acc[m][n]);
        __builtin_amdgcn_s_setprio(0);
    }

    for (int m=0;m<2;m++) for (int n=0;n<4;n++) {
        int grow = m0 + wr*32 + m*16 + lg*4;
        int gcol = n0 + wc*64 + n*16 + lr;
        for (int r=0;r<4;r++)
            C[(size_t)(grow+r) * N + gcol] = acc[m][n][r];
    }
}

// ---------------- causal flash attention: triple-buffer ring, ONE barrier per visit ----------
// 3 LDS buffers: stage(kt+2) writes buf (kt+2)%3 = buf (kt-1)%3, whose reads were consumed
// before any wave passed this visit's barrier (per-consumer lgkm waits) -> no mid-visit drain.
// LDS 48KB -> 3 blocks/CU; grid 1024 pure-LPT (qt descending) with hardware backfill.
__global__ __launch_bounds__(256, 3) void attn_fwd(
    const bf16* __restrict__ Qb, const bf16* __restrict__ Kb, const bf16* __restrict__ Vp,
    bf16* __restrict__ AO)
{
    __shared__ bf16 Ks[3][64*64];      // [buf][key][d], chunk-swizzled
    __shared__ bf16 Vs[3][64*64];      // [buf][d][k'],  chunk-swizzled
    int t = threadIdx.x;
    int lane = t & 63, w = t >> 6;
    int lr = lane & 15, lg = lane >> 4;
    int wgid = blockIdx.x;
    int qt = (NT-1) - (wgid >> 5);     // pure LPT: heaviest first (backfill-friendly)
    int bh = wgid & 31;
    int b = bh >> 4, h = bh & 15;
    size_t base = (size_t)bh * NS * HD;
    int q0 = qt*64 + w*16;

    bf16x8 qf[2];
    #pragma unroll
    for (int c=0;c<2;c++)
        qf[c] = *(const bf16x8*)&Qb[base + (size_t)(q0+lr)*HD + c*32 + lg*8];

    bf16x8 onesf;
    #pragma unroll
    for (int i=0;i<8;i++) onesf[i] = (bf16)1.0f;

    f32x4 o[4];
    f32x4 lacc = zero4();              // l[q=lr] via ones-row MFMA (k-dim reduction)
    #pragma unroll
    for (int n=0;n<4;n++) o[n] = zero4();
    f32x4 minit;                        // C-init = -12: constant softmax shift for free
    minit[0] = -12.f; minit[1] = -12.f; minit[2] = -12.f; minit[3] = -12.f;

    // staging: linear LDS dest + pre-swizzled global source (rule 21).
    int srow8 = lane >> 3;                        // 0..7
    int schunk = (lane & 7) ^ srow8;              // pre-swizzled source chunk
    int srcrow = w*8 + srow8;                     // 0..31 within a 32-row group
    const bf16* gK = Kb + base + (size_t)srcrow*HD + schunk*8;
    const bf16* gV = Vp + base + (size_t)srcrow*NS + schunk*8;

    auto stage = [&](int kt) {
        int buf = kt % 3;
        int kv0 = kt * 64;
        #pragma unroll
        for (int i=0;i<2;i++) {
            gload_lds16(gK + (size_t)(kv0 + i*32)*HD, &Ks[buf][(i*32 + w*8)*64]);
            gload_lds16(gV + (size_t)(i*32)*NS + kv0, &Vs[buf][(i*32 + w*8)*64]);
        }
    };

    stage(0);
    if (qt > 0) stage(1);              // outstanding: 8 stage loads

    for (int kt = 0; kt <= qt; kt++) {
        int cur = kt % 3;
        bool last = (kt == qt);
        // counted wait: tile kt landed; tile kt+1's 4 loads stay in flight
        if (!last) asm volatile("s_waitcnt vmcnt(4)" ::: "memory");
        else       asm volatile("s_waitcnt vmcnt(0)" ::: "memory");
        __builtin_amdgcn_s_barrier();                 // single barrier per visit
        __builtin_amdgcn_sched_barrier(0);

        if (kt + 2 <= qt) stage(kt + 2);              // writes buf (kt-1)%3: reads consumed

        const bf16* ksb = &Ks[cur][0];
        const bf16* vsb = &Vs[cur][0];

        // issue ALL K/V fragment reads; compiler schedules waits per-consumer
        bf16x8 kf[4][2], vf[2][4];
        #pragma unroll
        for (int kb=0;kb<4;kb++) {
            int row = kb*16 + lr;
            kf[kb][0] = *(const bf16x8*)&ksb[row*64 + ((lg     ^ (row&7))*8)];
            kf[kb][1] = *(const bf16x8*)&ksb[row*64 + (((4+lg) ^ (row&7))*8)];
        }
        #pragma unroll
        for (int c=0;c<2;c++)
            #pragma unroll
            for (int n=0;n<4;n++) {
                int row = n*16 + lr;
                vf[c][n] = *(const bf16x8*)&vsb[row*64 + (((c*4+lg) ^ (row&7))*8)];
            }

        // ---- S^T = K Q - 12: starts as soon as K-frags land; V reads land underneath ----
        f32x4 sc[4];
        __builtin_amdgcn_s_setprio(1);
        #pragma unroll
        for (int kb=0;kb<4;kb++) {
            sc[kb] = MFMA16(kf[kb][0], qf[0], minit);
            sc[kb] = MFMA16(kf[kb][1], qf[1], sc[kb]);
        }
        __builtin_amdgcn_s_setprio(0);

        if (last) {        // diagonal tile mask: k > q
            int qi = q0 + lr;
            #pragma unroll
            for (int kb=0;kb<4;kb++)
                #pragma unroll
                for (int rr=0;rr<4;rr++)
                    if (kt*64 + kb*16 + lg*4 + rr > qi) sc[kb][rr] = -__builtin_inff();
        }

        // ---- max-free softmax: P = exp2(sc) straight to bf16 fragments ----
        bf16x8 pa[2];
        #pragma unroll
        for (int c=0;c<2;c++) {
            bf16x8 v;
            #pragma unroll
            for (int i=0;i<8;i++) v[i] = (bf16)exp2f(sc[c*2 + (i>>2)][i&3]);
            pa[c] = v;
        }

        // ---- O += P V;  l += P . 1 (consumes vf -> all this visit's ds_reads complete) ----
        __builtin_amdgcn_s_setprio(1);
        #pragma unroll
        for (int c=0;c<2;c++) {
            lacc = MFMA16(onesf, pa[c], lacc);
            #pragma unroll
            for (int n=0;n<4;n++)
                o[n] = MFMA16(vf[c][n], pa[c], o[n]);
        }
        __builtin_amdgcn_s_setprio(0);
    }

    // epilogue: normalize, write [b,s,h,d] as bf16x4 chunks
    float inv = 1.0f / lacc[0];
    int q = q0 + lr;
    #pragma unroll
    for (int n=0;n<4;n++) {
        bf16x4 ov;
        #pragma unroll
        for (int rr=0;rr<4;rr++) ov[rr] = (bf16)(o[n][rr] * inv);
        *(bf16x4*)&AO[((size_t)(b*NS + q)*NH + h)*HD + n*16 + lg*4] = ov;
    }
}

extern "C" void kernel_launch(void* const* d_in, const int* in_sizes, int n_in,
                              void* d_out, int out_size, void* d_ws, size_t ws_size,
                              hipStream_t stream) {
    const float* x     = (const float*)d_in[0];
    const float* w_in  = (const float*)d_in[1];
    const float* w_out = (const float*)d_in[2];
    float* out = (float*)d_out;

    char* p = (char*)d_ws;
    bf16* xb    = (bf16*)p; p += (size_t)BS*ND*2;          // 8 MB
    bf16* winb  = (bf16*)p; p += (size_t)D3*ND*2;          // 6 MB
    bf16* woutb = (bf16*)p; p += (size_t)ND*ND*2;          // 2 MB
    bf16* Qb    = (bf16*)p; p += (size_t)NB*NH*NS*HD*2;    // 8 MB
    bf16* Kb    = (bf16*)p; p += (size_t)NB*NH*NS*HD*2;    // 8 MB
    bf16* Vp    = (bf16*)p; p += (size_t)NB*NH*NS*HD*2;    // 8 MB  (V^T, k-permuted, [bh][d][s'])
    bf16* AO    = (bf16*)p; p += (size_t)BS*ND*2;          // 8 MB
    float2* csT = (float2*)p; p += (size_t)NS*32*8;        // 512 KB cos/sin interleaved

    prep<<<(CVTN + NS*32)/256, 256, 0, stream>>>(x, w_in, w_out, xb, winb, woutb, csT);
    gemm_qkv<<<dim3(D3/192, BS/128), 256, 0, stream>>>(xb, winb, Qb, Kb, Vp, csT);
    attn_fwd<<<NB*NH*NT, 256, 0, stream>>>(Qb, Kb, Vp, AO);
    gemm_out<<<dim3(ND/128, BS/64), 256, 0, stream>>>(AO, woutb, out, BS, ND, ND);
}

// Round 25
// 89.897 us; speedup vs baseline: 1.0524x; 1.0524x over previous
//
#include <hip/hip_runtime.h>
#include <hip/hip_bf16.h>
#include <math.h>

// Problem constants
#define NB 2
#define NS 2048
#define ND 1024
#define NH 16
#define HD 64
#define BS (NB*NS)     // 4096 tokens
#define D3 (3*ND)      // 3072
#define NT (NS/64)     // 32 q-tiles of 64

typedef __bf16 bf16;
typedef __bf16 bf16x4 __attribute__((ext_vector_type(4)));
typedef __bf16 bf16x8 __attribute__((ext_vector_type(8)));
typedef float f32x4 __attribute__((ext_vector_type(4)));

#define MFMA16(a,b,c) __builtin_amdgcn_mfma_f32_16x16x32_bf16(a,b,c,0,0,0)

static __device__ inline f32x4 zero4() { f32x4 z; z[0]=0.f; z[1]=0.f; z[2]=0.f; z[3]=0.f; return z; }

// global -> LDS direct copy, 16B per lane; lds base must be wave-uniform.
__device__ __forceinline__ void gload_lds16(const bf16* g, bf16* l) {
    __builtin_amdgcn_global_load_lds(
        (__attribute__((address_space(1))) unsigned int*)g,
        (__attribute__((address_space(3))) unsigned int*)l, 16, 0, 0);
}

// ---------------- prep: f32->bf16 for x/w_in/w_out + RoPE float2 table, one launch ----------------
#define CVT1 (BS*ND/8)          // 524288
#define CVT2 (D3*ND/8)          // 393216
#define CVT3 (ND*ND/8)          // 131072
#define CVTN (CVT1+CVT2+CVT3)   // 1048576
__global__ __launch_bounds__(256) void prep(
    const float* __restrict__ x, const float* __restrict__ w_in, const float* __restrict__ w_out,
    bf16* __restrict__ xb, bf16* __restrict__ winb, bf16* __restrict__ woutb,
    float2* __restrict__ csT)
{
    int i = blockIdx.x * 256 + threadIdx.x;
    if (i < CVTN) {
        const float* in; bf16* out; int j;
        if (i < CVT1)            { in = x;     out = xb;    j = i; }
        else if (i < CVT1+CVT2)  { in = w_in;  out = winb;  j = i - CVT1; }
        else                     { in = w_out; out = woutb; j = i - CVT1 - CVT2; }
        const float4* p = (const float4*)in;
        float4 a = p[j*2], b = p[j*2+1];
        bf16x8 o;
        o[0]=(bf16)a.x; o[1]=(bf16)a.y; o[2]=(bf16)a.z; o[3]=(bf16)a.w;
        o[4]=(bf16)b.x; o[5]=(bf16)b.y; o[6]=(bf16)b.z; o[7]=(bf16)b.w;
        ((bf16x8*)out)[j] = o;
    } else {
        int k = i - CVTN;                      // [0, NS*32)
        int s = k >> 5, j = k & 31;
        float inv = __expf(-(float)j * (9.210340372f * 0.03125f));  // 10000^(-j/32)
        float ang = (float)s * inv;
        csT[k] = make_float2(cosf(ang), sinf(ang));
    }
}

// ---------------- QKV GEMM: 128x192 tile, 4 waves, 2 blocks/CU, 100% fill (r19/r21) ----------
__global__ __launch_bounds__(256, 2) void gemm_qkv(
    const bf16* __restrict__ A, const bf16* __restrict__ Bm,
    bf16* __restrict__ Qb, bf16* __restrict__ Kb, bf16* __restrict__ Vt,
    const float2* __restrict__ csT)
{
    __shared__ bf16 As[2][128*64];     // 32KB
    __shared__ bf16 Bs[2][192*64];     // 48KB
    int t = threadIdx.x;
    int lane = t & 63, w = t >> 6;      // 4 waves
    int lr = lane & 15, lg = lane >> 4;
    int m0 = blockIdx.y * 128, n0 = blockIdx.x * 192;

    int srow8 = lane >> 3;              // 0..7
    int schunk = (lane & 7) ^ srow8;    // pre-swizzled source chunk (rule 21)
    const bf16* gA = A  + (size_t)(m0 + srow8)*ND + schunk*8;
    const bf16* gB = Bm + (size_t)(n0 + srow8)*ND + schunk*8;

    auto stage = [&](int kt) {
        int buf = kt & 1, k0 = kt*64;
        #pragma unroll
        for (int i=0;i<4;i++) {
            int r0 = w*32 + i*8;                       // A rows, 32/wave
            gload_lds16(gA + (size_t)r0*ND + k0, &As[buf][r0*64]);
        }
        #pragma unroll
        for (int i=0;i<6;i++) {
            int r0 = w*48 + i*8;                       // B rows, 48/wave
            gload_lds16(gB + (size_t)r0*ND + k0, &Bs[buf][r0*64]);
        }
    };

    f32x4 acc[2][12];
    #pragma unroll
    for (int mm=0;mm<2;mm++)
        #pragma unroll
        for (int n=0;n<12;n++) acc[mm][n] = zero4();

    bf16x8 af[2][2], bfr[4][2];

    stage(0); stage(1);                 // 20 loads/wave outstanding

    for (int kt = 0; kt < 16; kt++) {
        int cur = kt & 1;
        const bf16* as = &As[cur][0];
        const bf16* bs = &Bs[cur][0];
        if (kt < 15) asm volatile("s_waitcnt vmcnt(10)" ::: "memory");
        else         asm volatile("s_waitcnt vmcnt(0)" ::: "memory");
        __builtin_amdgcn_s_barrier();
        __builtin_amdgcn_sched_barrier(0);

        // A fragments once per tile
        #pragma unroll
        for (int mm=0;mm<2;mm++) {
            int row = w*32 + mm*16 + lr;
            af[mm][0] = *(const bf16x8*)&as[row*64 + ((lg     ^ (row&7))*8)];
            af[mm][1] = *(const bf16x8*)&as[row*64 + (((4+lg) ^ (row&7))*8)];
        }

        // 3 groups of 4 B-fragments; group 2 releases the buffer + stages kt+2
        #pragma unroll
        for (int g=0; g<3; g++) {
            #pragma unroll
            for (int nn=0;nn<4;nn++) {
                int row = g*64 + nn*16 + lr;
                bfr[nn][0] = *(const bf16x8*)&bs[row*64 + ((lg     ^ (row&7))*8)];
                bfr[nn][1] = *(const bf16x8*)&bs[row*64 + (((4+lg) ^ (row&7))*8)];
            }
            asm volatile("s_waitcnt lgkmcnt(0)" ::: "memory");
            __builtin_amdgcn_sched_barrier(0);
            if (g == 2) {                              // all LDS reads of buf cur done
                __builtin_amdgcn_s_barrier();
                __builtin_amdgcn_sched_barrier(0);
                if (kt + 2 < 16) stage(kt + 2);        // refill buf cur for tile kt+2
            }
            __builtin_amdgcn_s_setprio(1);
            #pragma unroll
            for (int ks=0;ks<2;ks++)
                #pragma unroll
                for (int mm=0;mm<2;mm++)
                    #pragma unroll
                    for (int nn=0;nn<4;nn++)
                        acc[mm][g*4+nn] = MFMA16(af[mm][ks], bfr[nn][ks], acc[mm][g*4+nn]);
            __builtin_amdgcn_s_setprio(0);
        }
    }

    // ---- epilogue: per-64-col-group which; fused RoPE / V^T scatter ----
    const float qs = 0.125f * 1.44269504f;   // fold softmax scale + log2(e) into Q
    #pragma unroll
    for (int a=0;a<3;a++) {
        int colbase = n0 + a*64;
        int which = colbase >> 10;           // uniform per group
        if (which == 2) {
            #pragma unroll
            for (int p=0;p<4;p++)
                #pragma unroll
                for (int mm=0;mm<2;mm++) {
                    int gcol = colbase + p*16 + lr;
                    int h = (gcol & 1023) >> 6, d = gcol & 63;
                    int grow = m0 + w*32 + mm*16 + lg*4;
                    int b = grow >> 11, s0 = grow & (NS-1);
                    int shi = s0 & ~63, j = s0 & 63;
                    int kp = ((j>>5)&1)*32 + ((j>>2)&3)*8 + ((j>>4)&1)*4;
                    bf16x4 pv;
                    #pragma unroll
                    for (int r=0;r<4;r++) pv[r] = (bf16)acc[mm][a*4+p][r];
                    *(bf16x4*)&Vt[((size_t)((b*NH + h)*HD + d))*NS + shi + kp] = pv;
                }
        } else {
            bf16* dst = (which == 0) ? Qb : Kb;
            #pragma unroll
            for (int p=0;p<2;p++)
                #pragma unroll
                for (int mm=0;mm<2;mm++) {
                    int gcol = colbase + p*16 + lr;
                    int h = (gcol & 1023) >> 6, j = gcol & 63;   // j in [0,32)
                    int grow = m0 + w*32 + mm*16 + lg*4;
                    #pragma unroll
                    for (int r=0;r<4;r++) {
                        int gm = grow + r;
                        int b = gm >> 11, s = gm & (NS-1);
                        float2 cs = csT[(s<<5)+j];
                        float x1 = acc[mm][a*4+p][r], x2 = acc[mm][a*4+p+2][r];
                        float y1 = x1*cs.x - x2*cs.y;
                        float y2 = x2*cs.x + x1*cs.y;
                        if (which == 0) { y1 *= qs; y2 *= qs; }
                        size_t off = ((size_t)((b*NH + h)*NS + s))*HD;
                        dst[off + j]      = (bf16)y1;
                        dst[off + j + 32] = (bf16)y2;
                    }
                }
        }
    }
}

// ---------------- out-proj GEMM: 64x128 tile, 512 blocks = 2/CU (r23 overlap fix) ----------
__global__ __launch_bounds__(256, 2) void gemm_out(
    const bf16* __restrict__ A, const bf16* __restrict__ Bm,
    float* __restrict__ C, int M, int N, int K)
{
    __shared__ bf16 As[2][64*64];      // 16KB
    __shared__ bf16 Bs[2][128*64];     // 32KB
    int t = threadIdx.x;
    int lane = t & 63, w = t >> 6;
    int wr = w >> 1, wc = w & 1;       // 2x2 waves of 32x64
    int lr = lane & 15, lg = lane >> 4;
    int m0 = blockIdx.y * 64, n0 = blockIdx.x * 128;

    int srow = lane >> 3;                 // 0..7
    int schunk = (lane & 7) ^ srow;       // XOR-swizzled source chunk
    const bf16* gA = &A [(size_t)(m0 + srow)*K + schunk*8];
    const bf16* gB = &Bm[(size_t)(n0 + srow)*K + schunk*8];

    auto stage = [&](int kt) {
        int buf = kt & 1;
        int k0 = kt * 64;
        #pragma unroll
        for (int i=0;i<2;i++) {
            int r0 = w*16 + i*8;                       // A rows, 16/wave
            gload_lds16(gA + (size_t)r0*K + k0, &As[buf][r0*64]);
        }
        #pragma unroll
        for (int i=0;i<4;i++) {
            int r0 = w*32 + i*8;                       // B rows, 32/wave
            gload_lds16(gB + (size_t)r0*K + k0, &Bs[buf][r0*64]);
        }
    };

    f32x4 acc[2][4];
    for (int m=0;m<2;m++) for (int n=0;n<4;n++) acc[m][n] = zero4();

    int nt = K >> 6;
    stage(0);
    stage(1);                          // 12 loads/wave outstanding

    for (int kt = 0; kt < nt; kt++) {
        int cur = kt & 1;
        if (kt < nt-1) asm volatile("s_waitcnt vmcnt(6)" ::: "memory");
        else           asm volatile("s_waitcnt vmcnt(0)" ::: "memory");
        __builtin_amdgcn_s_barrier();
        __builtin_amdgcn_sched_barrier(0);

        bf16x8 af[2][2], bfr[2][4];
        #pragma unroll
        for (int ks=0;ks<2;ks++) {
            #pragma unroll
            for (int m=0;m<2;m++) {
                int row = wr*32 + m*16 + lr;
                af[ks][m] = *(const bf16x8*)&As[cur][row*64 + (((ks*4+lg) ^ (row&7))*8)];
            }
            #pragma unroll
            for (int n=0;n<4;n++) {
                int row = wc*64 + n*16 + lr;
                bfr[ks][n] = *(const bf16x8*)&Bs[cur][row*64 + (((ks*4+lg) ^ (row&7))*8)];
            }
        }
        asm volatile("s_waitcnt lgkmcnt(0)" ::: "memory");
        __builtin_amdgcn_sched_barrier(0);
        __builtin_amdgcn_s_barrier();
        __builtin_amdgcn_sched_barrier(0);

        if (kt + 2 < nt) stage(kt + 2);

        __builtin_amdgcn_s_setprio(1);
        #pragma unroll
        for (int ks=0;ks<2;ks++)
            #pragma unroll
            for (int m=0;m<2;m++)
                #pragma unroll
                for (int n=0;n<4;n++)
                    acc[m][n] = MFMA16(af[ks][m], bfr[ks][n], acc[m][n]);
        __builtin_amdgcn_s_setprio(0);
    }

    for (int m=0;m<2;m++) for (int n=0;n<4;n++) {
        int grow = m0 + wr*32 + m*16 + lg*4;
        int gcol = n0 + wc*64 + n*16 + lr;
        for (int r=0;r<4;r++)
            C[(size_t)(grow+r) * N + gcol] = acc[m][n][r];
    }
}

// ---------------- causal flash attention: overlapped visit schedule (r15, best measured) ------
__global__ __launch_bounds__(256, 4) void attn_fwd(
    const bf16* __restrict__ Qb, const bf16* __restrict__ Kb, const bf16* __restrict__ Vp,
    bf16* __restrict__ AO)
{
    __shared__ bf16 Ks[2][64*64];      // [buf][key][d], chunk-swizzled
    __shared__ bf16 Vs[2][64*64];      // [buf][d][k'],  chunk-swizzled
    int t = threadIdx.x;
    int lane = t & 63, w = t >> 6;
    int lr = lane & 15, lg = lane >> 4;
    int wgid = blockIdx.x;
    int g = wgid >> 5;
    int qt = (g < 8) ? 31 - g : (g < 16) ? g - 8 : (g < 24) ? 39 - g : g - 16;
    int bh = wgid & 31;
    int b = bh >> 4, h = bh & 15;
    size_t base = (size_t)bh * NS * HD;
    int q0 = qt*64 + w*16;

    bf16x8 qf[2];
    #pragma unroll
    for (int c=0;c<2;c++)
        qf[c] = *(const bf16x8*)&Qb[base + (size_t)(q0+lr)*HD + c*32 + lg*8];

    bf16x8 onesf;
    #pragma unroll
    for (int i=0;i<8;i++) onesf[i] = (bf16)1.0f;

    f32x4 o[4];
    f32x4 lacc = zero4();              // l[q=lr] via ones-row MFMA (k-dim reduction)
    #pragma unroll
    for (int n=0;n<4;n++) o[n] = zero4();
    f32x4 minit;                        // C-init = -12: constant softmax shift for free
    minit[0] = -12.f; minit[1] = -12.f; minit[2] = -12.f; minit[3] = -12.f;

    // staging: linear LDS dest + pre-swizzled global source (rule 21).
    int srow8 = lane >> 3;                        // 0..7
    int schunk = (lane & 7) ^ srow8;              // pre-swizzled source chunk
    int srcrow = w*8 + srow8;                     // 0..31 within a 32-row group
    const bf16* gK = Kb + base + (size_t)srcrow*HD + schunk*8;
    const bf16* gV = Vp + base + (size_t)srcrow*NS + schunk*8;

    auto stage = [&](int kt) {
        int buf = kt & 1;
        int kv0 = kt * 64;
        #pragma unroll
        for (int i=0;i<2;i++) {
            gload_lds16(gK + (size_t)(kv0 + i*32)*HD, &Ks[buf][(i*32 + w*8)*64]);
            gload_lds16(gV + (size_t)(i*32)*NS + kv0, &Vs[buf][(i*32 + w*8)*64]);
        }
    };

    stage(0);
    if (qt > 0) stage(1);              // outstanding: 8 stage loads

    for (int kt = 0; kt <= qt; kt++) {
        int cur = kt & 1;
        bool last = (kt == qt);
        if (!last) asm volatile("s_waitcnt vmcnt(4)" ::: "memory");
        else       asm volatile("s_waitcnt vmcnt(0)" ::: "memory");
        __builtin_amdgcn_s_barrier();
        __builtin_amdgcn_sched_barrier(0);

        const bf16* ksb = &Ks[cur][0];
        const bf16* vsb = &Vs[cur][0];

        // issue ALL K/V fragment reads; compiler schedules waits per-consumer
        bf16x8 kf[4][2], vf[2][4];
        #pragma unroll
        for (int kb=0;kb<4;kb++) {
            int row = kb*16 + lr;
            kf[kb][0] = *(const bf16x8*)&ksb[row*64 + ((lg     ^ (row&7))*8)];
            kf[kb][1] = *(const bf16x8*)&ksb[row*64 + (((4+lg) ^ (row&7))*8)];
        }
        #pragma unroll
        for (int c=0;c<2;c++)
            #pragma unroll
            for (int n=0;n<4;n++) {
                int row = n*16 + lr;
                vf[c][n] = *(const bf16x8*)&vsb[row*64 + (((c*4+lg) ^ (row&7))*8)];
            }

        // ---- S^T = K Q - 12: starts as soon as K-frags land; V reads land underneath ----
        f32x4 sc[4];
        __builtin_amdgcn_s_setprio(1);
        #pragma unroll
        for (int kb=0;kb<4;kb++) {
            sc[kb] = MFMA16(kf[kb][0], qf[0], minit);
            sc[kb] = MFMA16(kf[kb][1], qf[1], sc[kb]);
        }
        __builtin_amdgcn_s_setprio(0);

        if (last) {        // diagonal tile mask: k > q
            int qi = q0 + lr;
            #pragma unroll
            for (int kb=0;kb<4;kb++)
                #pragma unroll
                for (int rr=0;rr<4;rr++)
                    if (kt*64 + kb*16 + lg*4 + rr > qi) sc[kb][rr] = -__builtin_inff();
        }

        // ---- max-free softmax: P = exp2(sc) straight to bf16 fragments ----
        bf16x8 pa[2];
        #pragma unroll
        for (int c=0;c<2;c++) {
            bf16x8 v;
            #pragma unroll
            for (int i=0;i<8;i++) v[i] = (bf16)exp2f(sc[c*2 + (i>>2)][i&3]);
            pa[c] = v;
        }

        // buf release: all 16 reads done, then barrier
        asm volatile("s_waitcnt lgkmcnt(0)" ::: "memory");
        __builtin_amdgcn_sched_barrier(0);
        __builtin_amdgcn_s_barrier();
        __builtin_amdgcn_sched_barrier(0);

        if (kt + 2 <= qt) stage(kt + 2);              // refill buf cur for tile kt+2

        // ---- O += P V;  l += P . 1 (registers only; covers the stage issue) ----
        __builtin_amdgcn_s_setprio(1);
        #pragma unroll
        for (int c=0;c<2;c++) {
            lacc = MFMA16(onesf, pa[c], lacc);
            #pragma unroll
            for (int n=0;n<4;n++)
                o[n] = MFMA16(vf[c][n], pa[c], o[n]);
        }
        __builtin_amdgcn_s_setprio(0);
    }

    // epilogue: normalize, write [b,s,h,d] as bf16x4 chunks
    float inv = 1.0f / lacc[0];
    int q = q0 + lr;
    #pragma unroll
    for (int n=0;n<4;n++) {
        bf16x4 ov;
        #pragma unroll
        for (int rr=0;rr<4;rr++) ov[rr] = (bf16)(o[n][rr] * inv);
        *(bf16x4*)&AO[((size_t)(b*NS + q)*NH + h)*HD + n*16 + lg*4] = ov;
    }
}

extern "C" void kernel_launch(void* const* d_in, const int* in_sizes, int n_in,
                              void* d_out, int out_size, void* d_ws, size_t ws_size,
                              hipStream_t stream) {
    const float* x     = (const float*)d_in[0];
    const float* w_in  = (const float*)d_in[1];
    const float* w_out = (const float*)d_in[2];
    float* out = (float*)d_out;

    char* p = (char*)d_ws;
    bf16* xb    = (bf16*)p; p += (size_t)BS*ND*2;          // 8 MB
    bf16* winb  = (bf16*)p; p += (size_t)D3*ND*2;          // 6 MB
    bf16* woutb = (bf16*)p; p += (size_t)ND*ND*2;          // 2 MB
    bf16* Qb    = (bf16*)p; p += (size_t)NB*NH*NS*HD*2;    // 8 MB
    bf16* Kb    = (bf16*)p; p += (size_t)NB*NH*NS*HD*2;    // 8 MB
    bf16* Vp    = (bf16*)p; p += (size_t)NB*NH*NS*HD*2;    // 8 MB  (V^T, k-permuted, [bh][d][s'])
    bf16* AO    = (bf16*)p; p += (size_t)BS*ND*2;          // 8 MB
    float2* csT = (float2*)p; p += (size_t)NS*32*8;        // 512 KB cos/sin interleaved

    prep<<<(CVTN + NS*32)/256, 256, 0, stream>>>(x, w_in, w_out, xb, winb, woutb, csT);
    gemm_qkv<<<dim3(D3/192, BS/128), 256, 0, stream>>>(xb, winb, Qb, Kb, Vp, csT);
    attn_fwd<<<NB*NH*NT, 256, 0, stream>>>(Qb, Kb, Vp, AO);
    gemm_out<<<dim3(ND/128, BS/64), 256, 0, stream>>>(AO, woutb, out, BS, ND, ND);
}

// Round 26
// 89.539 us; speedup vs baseline: 1.0566x; 1.0040x over previous
//
#include <hip/hip_runtime.h>
#include <hip/hip_bf16.h>
#include <math.h>

// Problem constants
#define NB 2
#define NS 2048
#define ND 1024
#define NH 16
#define HD 64
#define BS (NB*NS)     // 4096 tokens
#define D3 (3*ND)      // 3072
#define NT (NS/64)     // 32 q-tiles of 64

typedef __bf16 bf16;
typedef __bf16 bf16x4 __attribute__((ext_vector_type(4)));
typedef __bf16 bf16x8 __attribute__((ext_vector_type(8)));
typedef float f32x4 __attribute__((ext_vector_type(4)));

#define MFMA16(a,b,c) __builtin_amdgcn_mfma_f32_16x16x32_bf16(a,b,c,0,0,0)

static __device__ inline f32x4 zero4() { f32x4 z; z[0]=0.f; z[1]=0.f; z[2]=0.f; z[3]=0.f; return z; }

// global -> LDS direct copy, 16B per lane; lds base must be wave-uniform.
__device__ __forceinline__ void gload_lds16(const bf16* g, bf16* l) {
    __builtin_amdgcn_global_load_lds(
        (__attribute__((address_space(1))) unsigned int*)g,
        (__attribute__((address_space(3))) unsigned int*)l, 16, 0, 0);
}

// ---------------- prep: f32->bf16 for x/w_in/w_out + RoPE float2 table, one launch ----------------
#define CVT1 (BS*ND/8)          // 524288
#define CVT2 (D3*ND/8)          // 393216
#define CVT3 (ND*ND/8)          // 131072
#define CVTN (CVT1+CVT2+CVT3)   // 1048576
__global__ __launch_bounds__(256) void prep(
    const float* __restrict__ x, const float* __restrict__ w_in, const float* __restrict__ w_out,
    bf16* __restrict__ xb, bf16* __restrict__ winb, bf16* __restrict__ woutb,
    float2* __restrict__ csT)
{
    int i = blockIdx.x * 256 + threadIdx.x;
    if (i < CVTN) {
        const float* in; bf16* out; int j;
        if (i < CVT1)            { in = x;     out = xb;    j = i; }
        else if (i < CVT1+CVT2)  { in = w_in;  out = winb;  j = i - CVT1; }
        else                     { in = w_out; out = woutb; j = i - CVT1 - CVT2; }
        const float4* p = (const float4*)in;
        float4 a = p[j*2], b = p[j*2+1];
        bf16x8 o;
        o[0]=(bf16)a.x; o[1]=(bf16)a.y; o[2]=(bf16)a.z; o[3]=(bf16)a.w;
        o[4]=(bf16)b.x; o[5]=(bf16)b.y; o[6]=(bf16)b.z; o[7]=(bf16)b.w;
        ((bf16x8*)out)[j] = o;
    } else {
        int k = i - CVTN;                      // [0, NS*32)
        int s = k >> 5, j = k & 31;
        float inv = __expf(-(float)j * (9.210340372f * 0.03125f));  // 10000^(-j/32)
        float ang = (float)s * inv;
        csT[k] = make_float2(cosf(ang), sinf(ang));
    }
}

// ---------------- QKV GEMM: 128x192 tile, 4 waves, 2 blocks/CU, 100% fill ----------------
// T1 XCD swizzle: 512 blocks, XCD k = orig&7 owns an 8x8 patch of (n-col, m-row) tiles
// -> per-XCD L2 working set ~5MB (8 B-panels + 8 A-panels) vs ~14MB unswizzled. Bijective.
__global__ __launch_bounds__(256, 2) void gemm_qkv(
    const bf16* __restrict__ A, const bf16* __restrict__ Bm,
    bf16* __restrict__ Qb, bf16* __restrict__ Kb, bf16* __restrict__ Vt,
    const float2* __restrict__ csT)
{
    __shared__ bf16 As[2][128*64];     // 32KB
    __shared__ bf16 Bs[2][192*64];     // 48KB
    int t = threadIdx.x;
    int lane = t & 63, w = t >> 6;      // 4 waves
    int lr = lane & 15, lg = lane >> 4;

    // XCD-aware 2D-patch remap (grid is flat 512)
    int orig = blockIdx.x;
    int xcd = orig & 7, idx = orig >> 3;          // idx in [0,64)
    int px = xcd & 1,  py = xcd >> 1;             // XCDs tiled 2 (n) x 4 (m)
    int wn = idx & 7,  wm = idx >> 3;             // within-patch 8 x 8
    int n0 = (px*8 + wn) * 192;                   // n-col tile
    int m0 = (py*8 + wm) * 128;                   // m-row tile

    int srow8 = lane >> 3;              // 0..7
    int schunk = (lane & 7) ^ srow8;    // pre-swizzled source chunk (rule 21)
    const bf16* gA = A  + (size_t)(m0 + srow8)*ND + schunk*8;
    const bf16* gB = Bm + (size_t)(n0 + srow8)*ND + schunk*8;

    auto stage = [&](int kt) {
        int buf = kt & 1, k0 = kt*64;
        #pragma unroll
        for (int i=0;i<4;i++) {
            int r0 = w*32 + i*8;                       // A rows, 32/wave
            gload_lds16(gA + (size_t)r0*ND + k0, &As[buf][r0*64]);
        }
        #pragma unroll
        for (int i=0;i<6;i++) {
            int r0 = w*48 + i*8;                       // B rows, 48/wave
            gload_lds16(gB + (size_t)r0*ND + k0, &Bs[buf][r0*64]);
        }
    };

    f32x4 acc[2][12];
    #pragma unroll
    for (int mm=0;mm<2;mm++)
        #pragma unroll
        for (int n=0;n<12;n++) acc[mm][n] = zero4();

    bf16x8 af[2][2], bfr[4][2];

    stage(0); stage(1);                 // 20 loads/wave outstanding

    for (int kt = 0; kt < 16; kt++) {
        int cur = kt & 1;
        const bf16* as = &As[cur][0];
        const bf16* bs = &Bs[cur][0];
        if (kt < 15) asm volatile("s_waitcnt vmcnt(10)" ::: "memory");
        else         asm volatile("s_waitcnt vmcnt(0)" ::: "memory");
        __builtin_amdgcn_s_barrier();
        __builtin_amdgcn_sched_barrier(0);

        // A fragments once per tile
        #pragma unroll
        for (int mm=0;mm<2;mm++) {
            int row = w*32 + mm*16 + lr;
            af[mm][0] = *(const bf16x8*)&as[row*64 + ((lg     ^ (row&7))*8)];
            af[mm][1] = *(const bf16x8*)&as[row*64 + (((4+lg) ^ (row&7))*8)];
        }

        // 3 groups of 4 B-fragments; group 2 releases the buffer + stages kt+2
        #pragma unroll
        for (int g=0; g<3; g++) {
            #pragma unroll
            for (int nn=0;nn<4;nn++) {
                int row = g*64 + nn*16 + lr;
                bfr[nn][0] = *(const bf16x8*)&bs[row*64 + ((lg     ^ (row&7))*8)];
                bfr[nn][1] = *(const bf16x8*)&bs[row*64 + (((4+lg) ^ (row&7))*8)];
            }
            asm volatile("s_waitcnt lgkmcnt(0)" ::: "memory");
            __builtin_amdgcn_sched_barrier(0);
            if (g == 2) {                              // all LDS reads of buf cur done
                __builtin_amdgcn_s_barrier();
                __builtin_amdgcn_sched_barrier(0);
                if (kt + 2 < 16) stage(kt + 2);        // refill buf cur for tile kt+2
            }
            __builtin_amdgcn_s_setprio(1);
            #pragma unroll
            for (int ks=0;ks<2;ks++)
                #pragma unroll
                for (int mm=0;mm<2;mm++)
                    #pragma unroll
                    for (int nn=0;nn<4;nn++)
                        acc[mm][g*4+nn] = MFMA16(af[mm][ks], bfr[nn][ks], acc[mm][g*4+nn]);
            __builtin_amdgcn_s_setprio(0);
        }
    }

    // ---- epilogue: per-64-col-group which; fused RoPE / V^T scatter ----
    const float qs = 0.125f * 1.44269504f;   // fold softmax scale + log2(e) into Q
    #pragma unroll
    for (int a=0;a<3;a++) {
        int colbase = n0 + a*64;
        int which = colbase >> 10;           // uniform per group
        if (which == 2) {
            #pragma unroll
            for (int p=0;p<4;p++)
                #pragma unroll
                for (int mm=0;mm<2;mm++) {
                    int gcol = colbase + p*16 + lr;
                    int h = (gcol & 1023) >> 6, d = gcol & 63;
                    int grow = m0 + w*32 + mm*16 + lg*4;
                    int b = grow >> 11, s0 = grow & (NS-1);
                    int shi = s0 & ~63, j = s0 & 63;
                    int kp = ((j>>5)&1)*32 + ((j>>2)&3)*8 + ((j>>4)&1)*4;
                    bf16x4 pv;
                    #pragma unroll
                    for (int r=0;r<4;r++) pv[r] = (bf16)acc[mm][a*4+p][r];
                    *(bf16x4*)&Vt[((size_t)((b*NH + h)*HD + d))*NS + shi + kp] = pv;
                }
        } else {
            bf16* dst = (which == 0) ? Qb : Kb;
            #pragma unroll
            for (int p=0;p<2;p++)
                #pragma unroll
                for (int mm=0;mm<2;mm++) {
                    int gcol = colbase + p*16 + lr;
                    int h = (gcol & 1023) >> 6, j = gcol & 63;   // j in [0,32)
                    int grow = m0 + w*32 + mm*16 + lg*4;
                    #pragma unroll
                    for (int r=0;r<4;r++) {
                        int gm = grow + r;
                        int b = gm >> 11, s = gm & (NS-1);
                        float2 cs = csT[(s<<5)+j];
                        float x1 = acc[mm][a*4+p][r], x2 = acc[mm][a*4+p+2][r];
                        float y1 = x1*cs.x - x2*cs.y;
                        float y2 = x2*cs.x + x1*cs.y;
                        if (which == 0) { y1 *= qs; y2 *= qs; }
                        size_t off = ((size_t)((b*NH + h)*NS + s))*HD;
                        dst[off + j]      = (bf16)y1;
                        dst[off + j + 32] = (bf16)y2;
                    }
                }
        }
    }
}

// ---------------- out-proj GEMM: 64x128 tile, 512 blocks = 2/CU (r23 overlap fix) ----------
__global__ __launch_bounds__(256, 2) void gemm_out(
    const bf16* __restrict__ A, const bf16* __restrict__ Bm,
    float* __restrict__ C, int M, int N, int K)
{
    __shared__ bf16 As[2][64*64];      // 16KB
    __shared__ bf16 Bs[2][128*64];     // 32KB
    int t = threadIdx.x;
    int lane = t & 63, w = t >> 6;
    int wr = w >> 1, wc = w & 1;       // 2x2 waves of 32x64
    int lr = lane & 15, lg = lane >> 4;
    int m0 = blockIdx.y * 64, n0 = blockIdx.x * 128;

    int srow = lane >> 3;                 // 0..7
    int schunk = (lane & 7) ^ srow;       // XOR-swizzled source chunk
    const bf16* gA = &A [(size_t)(m0 + srow)*K + schunk*8];
    const bf16* gB = &Bm[(size_t)(n0 + srow)*K + schunk*8];

    auto stage = [&](int kt) {
        int buf = kt & 1;
        int k0 = kt * 64;
        #pragma unroll
        for (int i=0;i<2;i++) {
            int r0 = w*16 + i*8;                       // A rows, 16/wave
            gload_lds16(gA + (size_t)r0*K + k0, &As[buf][r0*64]);
        }
        #pragma unroll
        for (int i=0;i<4;i++) {
            int r0 = w*32 + i*8;                       // B rows, 32/wave
            gload_lds16(gB + (size_t)r0*K + k0, &Bs[buf][r0*64]);
        }
    };

    f32x4 acc[2][4];
    for (int m=0;m<2;m++) for (int n=0;n<4;n++) acc[m][n] = zero4();

    int nt = K >> 6;
    stage(0);
    stage(1);                          // 12 loads/wave outstanding

    for (int kt = 0; kt < nt; kt++) {
        int cur = kt & 1;
        if (kt < nt-1) asm volatile("s_waitcnt vmcnt(6)" ::: "memory");
        else           asm volatile("s_waitcnt vmcnt(0)" ::: "memory");
        __builtin_amdgcn_s_barrier();
        __builtin_amdgcn_sched_barrier(0);

        bf16x8 af[2][2], bfr[2][4];
        #pragma unroll
        for (int ks=0;ks<2;ks++) {
            #pragma unroll
            for (int m=0;m<2;m++) {
                int row = wr*32 + m*16 + lr;
                af[ks][m] = *(const bf16x8*)&As[cur][row*64 + (((ks*4+lg) ^ (row&7))*8)];
            }
            #pragma unroll
            for (int n=0;n<4;n++) {
                int row = wc*64 + n*16 + lr;
                bfr[ks][n] = *(const bf16x8*)&Bs[cur][row*64 + (((ks*4+lg) ^ (row&7))*8)];
            }
        }
        asm volatile("s_waitcnt lgkmcnt(0)" ::: "memory");
        __builtin_amdgcn_sched_barrier(0);
        __builtin_amdgcn_s_barrier();
        __builtin_amdgcn_sched_barrier(0);

        if (kt + 2 < nt) stage(kt + 2);

        __builtin_amdgcn_s_setprio(1);
        #pragma unroll
        for (int ks=0;ks<2;ks++)
            #pragma unroll
            for (int m=0;m<2;m++)
                #pragma unroll
                for (int n=0;n<4;n++)
                    acc[m][n] = MFMA16(af[ks][m], bfr[ks][n], acc[m][n]);
        __builtin_amdgcn_s_setprio(0);
    }

    for (int m=0;m<2;m++) for (int n=0;n<4;n++) {
        int grow = m0 + wr*32 + m*16 + lg*4;
        int gcol = n0 + wc*64 + n*16 + lr;
        for (int r=0;r<4;r++)
            C[(size_t)(grow+r) * N + gcol] = acc[m][n][r];
    }
}

// ---------------- causal flash attention: overlapped visit schedule (r15, best measured) ------
__global__ __launch_bounds__(256, 4) void attn_fwd(
    const bf16* __restrict__ Qb, const bf16* __restrict__ Kb, const bf16* __restrict__ Vp,
    bf16* __restrict__ AO)
{
    __shared__ bf16 Ks[2][64*64];      // [buf][key][d], chunk-swizzled
    __shared__ bf16 Vs[2][64*64];      // [buf][d][k'],  chunk-swizzled
    int t = threadIdx.x;
    int lane = t & 63, w = t >> 6;
    int lr = lane & 15, lg = lane >> 4;
    int wgid = blockIdx.x;
    int g = wgid >> 5;
    int qt = (g < 8) ? 31 - g : (g < 16) ? g - 8 : (g < 24) ? 39 - g : g - 16;
    int bh = wgid & 31;
    int b = bh >> 4, h = bh & 15;
    size_t base = (size_t)bh * NS * HD;
    int q0 = qt*64 + w*16;

    bf16x8 qf[2];
    #pragma unroll
    for (int c=0;c<2;c++)
        qf[c] = *(const bf16x8*)&Qb[base + (size_t)(q0+lr)*HD + c*32 + lg*8];

    bf16x8 onesf;
    #pragma unroll
    for (int i=0;i<8;i++) onesf[i] = (bf16)1.0f;

    f32x4 o[4];
    f32x4 lacc = zero4();              // l[q=lr] via ones-row MFMA (k-dim reduction)
    #pragma unroll
    for (int n=0;n<4;n++) o[n] = zero4();
    f32x4 minit;                        // C-init = -12: constant softmax shift for free
    minit[0] = -12.f; minit[1] = -12.f; minit[2] = -12.f; minit[3] = -12.f;

    // staging: linear LDS dest + pre-swizzled global source (rule 21).
    int srow8 = lane >> 3;                        // 0..7
    int schunk = (lane & 7) ^ srow8;              // pre-swizzled source chunk
    int srcrow = w*8 + srow8;                     // 0..31 within a 32-row group
    const bf16* gK = Kb + base + (size_t)srcrow*HD + schunk*8;
    const bf16* gV = Vp + base + (size_t)srcrow*NS + schunk*8;

    auto stage = [&](int kt) {
        int buf = kt & 1;
        int kv0 = kt * 64;
        #pragma unroll
        for (int i=0;i<2;i++) {
            gload_lds16(gK + (size_t)(kv0 + i*32)*HD, &Ks[buf][(i*32 + w*8)*64]);
            gload_lds16(gV + (size_t)(i*32)*NS + kv0, &Vs[buf][(i*32 + w*8)*64]);
        }
    };

    stage(0);
    if (qt > 0) stage(1);              // outstanding: 8 stage loads

    for (int kt = 0; kt <= qt; kt++) {
        int cur = kt & 1;
        bool last = (kt == qt);
        if (!last) asm volatile("s_waitcnt vmcnt(4)" ::: "memory");
        else       asm volatile("s_waitcnt vmcnt(0)" ::: "memory");
        __builtin_amdgcn_s_barrier();
        __builtin_amdgcn_sched_barrier(0);

        const bf16* ksb = &Ks[cur][0];
        const bf16* vsb = &Vs[cur][0];

        // issue ALL K/V fragment reads; compiler schedules waits per-consumer
        bf16x8 kf[4][2], vf[2][4];
        #pragma unroll
        for (int kb=0;kb<4;kb++) {
            int row = kb*16 + lr;
            kf[kb][0] = *(const bf16x8*)&ksb[row*64 + ((lg     ^ (row&7))*8)];
            kf[kb][1] = *(const bf16x8*)&ksb[row*64 + (((4+lg) ^ (row&7))*8)];
        }
        #pragma unroll
        for (int c=0;c<2;c++)
            #pragma unroll
            for (int n=0;n<4;n++) {
                int row = n*16 + lr;
                vf[c][n] = *(const bf16x8*)&vsb[row*64 + (((c*4+lg) ^ (row&7))*8)];
            }

        // ---- S^T = K Q - 12: starts as soon as K-frags land; V reads land underneath ----
        f32x4 sc[4];
        __builtin_amdgcn_s_setprio(1);
        #pragma unroll
        for (int kb=0;kb<4;kb++) {
            sc[kb] = MFMA16(kf[kb][0], qf[0], minit);
            sc[kb] = MFMA16(kf[kb][1], qf[1], sc[kb]);
        }
        __builtin_amdgcn_s_setprio(0);

        if (last) {        // diagonal tile mask: k > q
            int qi = q0 + lr;
            #pragma unroll
            for (int kb=0;kb<4;kb++)
                #pragma unroll
                for (int rr=0;rr<4;rr++)
                    if (kt*64 + kb*16 + lg*4 + rr > qi) sc[kb][rr] = -__builtin_inff();
        }

        // ---- max-free softmax: P = exp2(sc) straight to bf16 fragments ----
        bf16x8 pa[2];
        #pragma unroll
        for (int c=0;c<2;c++) {
            bf16x8 v;
            #pragma unroll
            for (int i=0;i<8;i++) v[i] = (bf16)exp2f(sc[c*2 + (i>>2)][i&3]);
            pa[c] = v;
        }

        // buf release: all 16 reads done, then barrier
        asm volatile("s_waitcnt lgkmcnt(0)" ::: "memory");
        __builtin_amdgcn_sched_barrier(0);
        __builtin_amdgcn_s_barrier();
        __builtin_amdgcn_sched_barrier(0);

        if (kt + 2 <= qt) stage(kt + 2);              // refill buf cur for tile kt+2

        // ---- O += P V;  l += P . 1 (registers only; covers the stage issue) ----
        __builtin_amdgcn_s_setprio(1);
        #pragma unroll
        for (int c=0;c<2;c++) {
            lacc = MFMA16(onesf, pa[c], lacc);
            #pragma unroll
            for (int n=0;n<4;n++)
                o[n] = MFMA16(vf[c][n], pa[c], o[n]);
        }
        __builtin_amdgcn_s_setprio(0);
    }

    // epilogue: normalize, write [b,s,h,d] as bf16x4 chunks
    float inv = 1.0f / lacc[0];
    int q = q0 + lr;
    #pragma unroll
    for (int n=0;n<4;n++) {
        bf16x4 ov;
        #pragma unroll
        for (int rr=0;rr<4;rr++) ov[rr] = (bf16)(o[n][rr] * inv);
        *(bf16x4*)&AO[((size_t)(b*NS + q)*NH + h)*HD + n*16 + lg*4] = ov;
    }
}

extern "C" void kernel_launch(void* const* d_in, const int* in_sizes, int n_in,
                              void* d_out, int out_size, void* d_ws, size_t ws_size,
                              hipStream_t stream) {
    const float* x     = (const float*)d_in[0];
    const float* w_in  = (const float*)d_in[1];
    const float* w_out = (const float*)d_in[2];
    float* out = (float*)d_out;

    char* p = (char*)d_ws;
    bf16* xb    = (bf16*)p; p += (size_t)BS*ND*2;          // 8 MB
    bf16* winb  = (bf16*)p; p += (size_t)D3*ND*2;          // 6 MB
    bf16* woutb = (bf16*)p; p += (size_t)ND*ND*2;          // 2 MB
    bf16* Qb    = (bf16*)p; p += (size_t)NB*NH*NS*HD*2;    // 8 MB
    bf16* Kb    = (bf16*)p; p += (size_t)NB*NH*NS*HD*2;    // 8 MB
    bf16* Vp    = (bf16*)p; p += (size_t)NB*NH*NS*HD*2;    // 8 MB  (V^T, k-permuted, [bh][d][s'])
    bf16* AO    = (bf16*)p; p += (size_t)BS*ND*2;          // 8 MB
    float2* csT = (float2*)p; p += (size_t)NS*32*8;        // 512 KB cos/sin interleaved

    prep<<<(CVTN + NS*32)/256, 256, 0, stream>>>(x, w_in, w_out, xb, winb, woutb, csT);
    gemm_qkv<<<512, 256, 0, stream>>>(xb, winb, Qb, Kb, Vp, csT);
    attn_fwd<<<NB*NH*NT, 256, 0, stream>>>(Qb, Kb, Vp, AO);
    gemm_out<<<dim3(ND/128, BS/64), 256, 0, stream>>>(AO, woutb, out, BS, ND, ND);
}

// Round 27
// 89.512 us; speedup vs baseline: 1.0569x; 1.0003x over previous
//
#include <hip/hip_runtime.h>
#include <hip/hip_bf16.h>
#include <math.h>

// Problem constants
#define NB 2
#define NS 2048
#define ND 1024
#define NH 16
#define HD 64
#define BS (NB*NS)     // 4096 tokens
#define D3 (3*ND)      // 3072
#define NT (NS/64)     // 32 q-tiles of 64

typedef __bf16 bf16;
typedef __bf16 bf16x4 __attribute__((ext_vector_type(4)));
typedef __bf16 bf16x8 __attribute__((ext_vector_type(8)));
typedef float f32x4 __attribute__((ext_vector_type(4)));

#define MFMA16(a,b,c) __builtin_amdgcn_mfma_f32_16x16x32_bf16(a,b,c,0,0,0)

static __device__ inline f32x4 zero4() { f32x4 z; z[0]=0.f; z[1]=0.f; z[2]=0.f; z[3]=0.f; return z; }

// global -> LDS direct copy, 16B per lane; lds base must be wave-uniform.
__device__ __forceinline__ void gload_lds16(const bf16* g, bf16* l) {
    __builtin_amdgcn_global_load_lds(
        (__attribute__((address_space(1))) unsigned int*)g,
        (__attribute__((address_space(3))) unsigned int*)l, 16, 0, 0);
}

// ---------------- prep: f32->bf16 for x/w_in/w_out + RoPE float2 table, one launch ----------------
#define CVT1 (BS*ND/8)          // 524288
#define CVT2 (D3*ND/8)          // 393216
#define CVT3 (ND*ND/8)          // 131072
#define CVTN (CVT1+CVT2+CVT3)   // 1048576
__global__ __launch_bounds__(256) void prep(
    const float* __restrict__ x, const float* __restrict__ w_in, const float* __restrict__ w_out,
    bf16* __restrict__ xb, bf16* __restrict__ winb, bf16* __restrict__ woutb,
    float2* __restrict__ csT)
{
    int i = blockIdx.x * 256 + threadIdx.x;
    if (i < CVTN) {
        const float* in; bf16* out; int j;
        if (i < CVT1)            { in = x;     out = xb;    j = i; }
        else if (i < CVT1+CVT2)  { in = w_in;  out = winb;  j = i - CVT1; }
        else                     { in = w_out; out = woutb; j = i - CVT1 - CVT2; }
        const float4* p = (const float4*)in;
        float4 a = p[j*2], b = p[j*2+1];
        bf16x8 o;
        o[0]=(bf16)a.x; o[1]=(bf16)a.y; o[2]=(bf16)a.z; o[3]=(bf16)a.w;
        o[4]=(bf16)b.x; o[5]=(bf16)b.y; o[6]=(bf16)b.z; o[7]=(bf16)b.w;
        ((bf16x8*)out)[j] = o;
    } else {
        int k = i - CVTN;                      // [0, NS*32)
        int s = k >> 5, j = k & 31;
        float inv = __expf(-(float)j * (9.210340372f * 0.03125f));  // 10000^(-j/32)
        float ang = (float)s * inv;
        csT[k] = make_float2(cosf(ang), sinf(ang));
    }
}

// ---------------- QKV GEMM: 128x192 tile, 4 waves, 2 blocks/CU, 100% fill ----------------
// T1 XCD swizzle: 512 blocks, XCD k = orig&7 owns an 8x8 patch of (n-col, m-row) tiles.
__global__ __launch_bounds__(256, 2) void gemm_qkv(
    const bf16* __restrict__ A, const bf16* __restrict__ Bm,
    bf16* __restrict__ Qb, bf16* __restrict__ Kb, bf16* __restrict__ Vt,
    const float2* __restrict__ csT)
{
    __shared__ bf16 As[2][128*64];     // 32KB
    __shared__ bf16 Bs[2][192*64];     // 48KB
    int t = threadIdx.x;
    int lane = t & 63, w = t >> 6;      // 4 waves
    int lr = lane & 15, lg = lane >> 4;

    // XCD-aware 2D-patch remap (grid is flat 512)
    int orig = blockIdx.x;
    int xcd = orig & 7, idx = orig >> 3;          // idx in [0,64)
    int px = xcd & 1,  py = xcd >> 1;             // XCDs tiled 2 (n) x 4 (m)
    int wn = idx & 7,  wm = idx >> 3;             // within-patch 8 x 8
    int n0 = (px*8 + wn) * 192;                   // n-col tile
    int m0 = (py*8 + wm) * 128;                   // m-row tile

    int srow8 = lane >> 3;              // 0..7
    int schunk = (lane & 7) ^ srow8;    // pre-swizzled source chunk (rule 21)
    const bf16* gA = A  + (size_t)(m0 + srow8)*ND + schunk*8;
    const bf16* gB = Bm + (size_t)(n0 + srow8)*ND + schunk*8;

    auto stage = [&](int kt) {
        int buf = kt & 1, k0 = kt*64;
        #pragma unroll
        for (int i=0;i<4;i++) {
            int r0 = w*32 + i*8;                       // A rows, 32/wave
            gload_lds16(gA + (size_t)r0*ND + k0, &As[buf][r0*64]);
        }
        #pragma unroll
        for (int i=0;i<6;i++) {
            int r0 = w*48 + i*8;                       // B rows, 48/wave
            gload_lds16(gB + (size_t)r0*ND + k0, &Bs[buf][r0*64]);
        }
    };

    f32x4 acc[2][12];
    #pragma unroll
    for (int mm=0;mm<2;mm++)
        #pragma unroll
        for (int n=0;n<12;n++) acc[mm][n] = zero4();

    bf16x8 af[2][2], bfr[4][2];

    stage(0); stage(1);                 // 20 loads/wave outstanding

    for (int kt = 0; kt < 16; kt++) {
        int cur = kt & 1;
        const bf16* as = &As[cur][0];
        const bf16* bs = &Bs[cur][0];
        if (kt < 15) asm volatile("s_waitcnt vmcnt(10)" ::: "memory");
        else         asm volatile("s_waitcnt vmcnt(0)" ::: "memory");
        __builtin_amdgcn_s_barrier();
        __builtin_amdgcn_sched_barrier(0);

        // A fragments once per tile
        #pragma unroll
        for (int mm=0;mm<2;mm++) {
            int row = w*32 + mm*16 + lr;
            af[mm][0] = *(const bf16x8*)&as[row*64 + ((lg     ^ (row&7))*8)];
            af[mm][1] = *(const bf16x8*)&as[row*64 + (((4+lg) ^ (row&7))*8)];
        }

        // 3 groups of 4 B-fragments; group 2 releases the buffer + stages kt+2
        #pragma unroll
        for (int g=0; g<3; g++) {
            #pragma unroll
            for (int nn=0;nn<4;nn++) {
                int row = g*64 + nn*16 + lr;
                bfr[nn][0] = *(const bf16x8*)&bs[row*64 + ((lg     ^ (row&7))*8)];
                bfr[nn][1] = *(const bf16x8*)&bs[row*64 + (((4+lg) ^ (row&7))*8)];
            }
            asm volatile("s_waitcnt lgkmcnt(0)" ::: "memory");
            __builtin_amdgcn_sched_barrier(0);
            if (g == 2) {                              // all LDS reads of buf cur done
                __builtin_amdgcn_s_barrier();
                __builtin_amdgcn_sched_barrier(0);
                if (kt + 2 < 16) stage(kt + 2);        // refill buf cur for tile kt+2
            }
            __builtin_amdgcn_s_setprio(1);
            #pragma unroll
            for (int ks=0;ks<2;ks++)
                #pragma unroll
                for (int mm=0;mm<2;mm++)
                    #pragma unroll
                    for (int nn=0;nn<4;nn++)
                        acc[mm][g*4+nn] = MFMA16(af[mm][ks], bfr[nn][ks], acc[mm][g*4+nn]);
            __builtin_amdgcn_s_setprio(0);
        }
    }

    // ---- epilogue: per-64-col-group which; fused RoPE / V^T scatter ----
    const float qs = 0.125f * 1.44269504f;   // fold softmax scale + log2(e) into Q
    #pragma unroll
    for (int a=0;a<3;a++) {
        int colbase = n0 + a*64;
        int which = colbase >> 10;           // uniform per group
        if (which == 2) {
            #pragma unroll
            for (int p=0;p<4;p++)
                #pragma unroll
                for (int mm=0;mm<2;mm++) {
                    int gcol = colbase + p*16 + lr;
                    int h = (gcol & 1023) >> 6, d = gcol & 63;
                    int grow = m0 + w*32 + mm*16 + lg*4;
                    int b = grow >> 11, s0 = grow & (NS-1);
                    int shi = s0 & ~63, j = s0 & 63;
                    int kp = ((j>>5)&1)*32 + ((j>>2)&3)*8 + ((j>>4)&1)*4;
                    bf16x4 pv;
                    #pragma unroll
                    for (int r=0;r<4;r++) pv[r] = (bf16)acc[mm][a*4+p][r];
                    *(bf16x4*)&Vt[((size_t)((b*NH + h)*HD + d))*NS + shi + kp] = pv;
                }
        } else {
            bf16* dst = (which == 0) ? Qb : Kb;
            #pragma unroll
            for (int p=0;p<2;p++)
                #pragma unroll
                for (int mm=0;mm<2;mm++) {
                    int gcol = colbase + p*16 + lr;
                    int h = (gcol & 1023) >> 6, j = gcol & 63;   // j in [0,32)
                    int grow = m0 + w*32 + mm*16 + lg*4;
                    #pragma unroll
                    for (int r=0;r<4;r++) {
                        int gm = grow + r;
                        int b = gm >> 11, s = gm & (NS-1);
                        float2 cs = csT[(s<<5)+j];
                        float x1 = acc[mm][a*4+p][r], x2 = acc[mm][a*4+p+2][r];
                        float y1 = x1*cs.x - x2*cs.y;
                        float y2 = x2*cs.x + x1*cs.y;
                        if (which == 0) { y1 *= qs; y2 *= qs; }
                        size_t off = ((size_t)((b*NH + h)*NS + s))*HD;
                        dst[off + j]      = (bf16)y1;
                        dst[off + j + 32] = (bf16)y2;
                    }
                }
        }
    }
}

// ---------------- out-proj GEMM: 64x128 tile, 512 blocks = 2/CU + T1 XCD swizzle ----------
// XCD k = orig&7 owns n-col k (one 256KB woutb panel pinned per XCD L2); m-rows stream.
__global__ __launch_bounds__(256, 2) void gemm_out(
    const bf16* __restrict__ A, const bf16* __restrict__ Bm,
    float* __restrict__ C, int M, int N, int K)
{
    __shared__ bf16 As[2][64*64];      // 16KB
    __shared__ bf16 Bs[2][128*64];     // 32KB
    int t = threadIdx.x;
    int lane = t & 63, w = t >> 6;
    int wr = w >> 1, wc = w & 1;       // 2x2 waves of 32x64
    int lr = lane & 15, lg = lane >> 4;
    int orig = blockIdx.x;
    int n0 = (orig & 7) * 128;         // XCD owns one B panel
    int m0 = (orig >> 3) * 64;

    int srow = lane >> 3;                 // 0..7
    int schunk = (lane & 7) ^ srow;       // XOR-swizzled source chunk
    const bf16* gA = &A [(size_t)(m0 + srow)*K + schunk*8];
    const bf16* gB = &Bm[(size_t)(n0 + srow)*K + schunk*8];

    auto stage = [&](int kt) {
        int buf = kt & 1;
        int k0 = kt * 64;
        #pragma unroll
        for (int i=0;i<2;i++) {
            int r0 = w*16 + i*8;                       // A rows, 16/wave
            gload_lds16(gA + (size_t)r0*K + k0, &As[buf][r0*64]);
        }
        #pragma unroll
        for (int i=0;i<4;i++) {
            int r0 = w*32 + i*8;                       // B rows, 32/wave
            gload_lds16(gB + (size_t)r0*K + k0, &Bs[buf][r0*64]);
        }
    };

    f32x4 acc[2][4];
    for (int m=0;m<2;m++) for (int n=0;n<4;n++) acc[m][n] = zero4();

    int nt = K >> 6;
    stage(0);
    stage(1);                          // 12 loads/wave outstanding

    for (int kt = 0; kt < nt; kt++) {
        int cur = kt & 1;
        if (kt < nt-1) asm volatile("s_waitcnt vmcnt(6)" ::: "memory");
        else           asm volatile("s_waitcnt vmcnt(0)" ::: "memory");
        __builtin_amdgcn_s_barrier();
        __builtin_amdgcn_sched_barrier(0);

        bf16x8 af[2][2], bfr[2][4];
        #pragma unroll
        for (int ks=0;ks<2;ks++) {
            #pragma unroll
            for (int m=0;m<2;m++) {
                int row = wr*32 + m*16 + lr;
                af[ks][m] = *(const bf16x8*)&As[cur][row*64 + (((ks*4+lg) ^ (row&7))*8)];
            }
            #pragma unroll
            for (int n=0;n<4;n++) {
                int row = wc*64 + n*16 + lr;
                bfr[ks][n] = *(const bf16x8*)&Bs[cur][row*64 + (((ks*4+lg) ^ (row&7))*8)];
            }
        }
        asm volatile("s_waitcnt lgkmcnt(0)" ::: "memory");
        __builtin_amdgcn_sched_barrier(0);
        __builtin_amdgcn_s_barrier();
        __builtin_amdgcn_sched_barrier(0);

        if (kt + 2 < nt) stage(kt + 2);

        __builtin_amdgcn_s_setprio(1);
        #pragma unroll
        for (int ks=0;ks<2;ks++)
            #pragma unroll
            for (int m=0;m<2;m++)
                #pragma unroll
                for (int n=0;n<4;n++)
                    acc[m][n] = MFMA16(af[ks][m], bfr[ks][n], acc[m][n]);
        __builtin_amdgcn_s_setprio(0);
    }

    for (int m=0;m<2;m++) for (int n=0;n<4;n++) {
        int grow = m0 + wr*32 + m*16 + lg*4;
        int gcol = n0 + wc*64 + n*16 + lr;
        for (int r=0;r<4;r++)
            C[(size_t)(grow+r) * N + gcol] = acc[m][n][r];
    }
}

// ---------------- causal flash attention: overlapped visit schedule (r15, best measured) ------
__global__ __launch_bounds__(256, 4) void attn_fwd(
    const bf16* __restrict__ Qb, const bf16* __restrict__ Kb, const bf16* __restrict__ Vp,
    bf16* __restrict__ AO)
{
    __shared__ bf16 Ks[2][64*64];      // [buf][key][d], chunk-swizzled
    __shared__ bf16 Vs[2][64*64];      // [buf][d][k'],  chunk-swizzled
    int t = threadIdx.x;
    int lane = t & 63, w = t >> 6;
    int lr = lane & 15, lg = lane >> 4;
    int wgid = blockIdx.x;
    int g = wgid >> 5;
    int qt = (g < 8) ? 31 - g : (g < 16) ? g - 8 : (g < 24) ? 39 - g : g - 16;
    int bh = wgid & 31;
    int b = bh >> 4, h = bh & 15;
    size_t base = (size_t)bh * NS * HD;
    int q0 = qt*64 + w*16;

    bf16x8 qf[2];
    #pragma unroll
    for (int c=0;c<2;c++)
        qf[c] = *(const bf16x8*)&Qb[base + (size_t)(q0+lr)*HD + c*32 + lg*8];

    bf16x8 onesf;
    #pragma unroll
    for (int i=0;i<8;i++) onesf[i] = (bf16)1.0f;

    f32x4 o[4];
    f32x4 lacc = zero4();              // l[q=lr] via ones-row MFMA (k-dim reduction)
    #pragma unroll
    for (int n=0;n<4;n++) o[n] = zero4();
    f32x4 minit;                        // C-init = -12: constant softmax shift for free
    minit[0] = -12.f; minit[1] = -12.f; minit[2] = -12.f; minit[3] = -12.f;

    // staging: linear LDS dest + pre-swizzled global source (rule 21).
    int srow8 = lane >> 3;                        // 0..7
    int schunk = (lane & 7) ^ srow8;              // pre-swizzled source chunk
    int srcrow = w*8 + srow8;                     // 0..31 within a 32-row group
    const bf16* gK = Kb + base + (size_t)srcrow*HD + schunk*8;
    const bf16* gV = Vp + base + (size_t)srcrow*NS + schunk*8;

    auto stage = [&](int kt) {
        int buf = kt & 1;
        int kv0 = kt * 64;
        #pragma unroll
        for (int i=0;i<2;i++) {
            gload_lds16(gK + (size_t)(kv0 + i*32)*HD, &Ks[buf][(i*32 + w*8)*64]);
            gload_lds16(gV + (size_t)(i*32)*NS + kv0, &Vs[buf][(i*32 + w*8)*64]);
        }
    };

    stage(0);
    if (qt > 0) stage(1);              // outstanding: 8 stage loads

    for (int kt = 0; kt <= qt; kt++) {
        int cur = kt & 1;
        bool last = (kt == qt);
        if (!last) asm volatile("s_waitcnt vmcnt(4)" ::: "memory");
        else       asm volatile("s_waitcnt vmcnt(0)" ::: "memory");
        __builtin_amdgcn_s_barrier();
        __builtin_amdgcn_sched_barrier(0);

        const bf16* ksb = &Ks[cur][0];
        const bf16* vsb = &Vs[cur][0];

        // issue ALL K/V fragment reads; compiler schedules waits per-consumer
        bf16x8 kf[4][2], vf[2][4];
        #pragma unroll
        for (int kb=0;kb<4;kb++) {
            int row = kb*16 + lr;
            kf[kb][0] = *(const bf16x8*)&ksb[row*64 + ((lg     ^ (row&7))*8)];
            kf[kb][1] = *(const bf16x8*)&ksb[row*64 + (((4+lg) ^ (row&7))*8)];
        }
        #pragma unroll
        for (int c=0;c<2;c++)
            #pragma unroll
            for (int n=0;n<4;n++) {
                int row = n*16 + lr;
                vf[c][n] = *(const bf16x8*)&vsb[row*64 + (((c*4+lg) ^ (row&7))*8)];
            }

        // ---- S^T = K Q - 12: starts as soon as K-frags land; V reads land underneath ----
        f32x4 sc[4];
        __builtin_amdgcn_s_setprio(1);
        #pragma unroll
        for (int kb=0;kb<4;kb++) {
            sc[kb] = MFMA16(kf[kb][0], qf[0], minit);
            sc[kb] = MFMA16(kf[kb][1], qf[1], sc[kb]);
        }
        __builtin_amdgcn_s_setprio(0);

        if (last) {        // diagonal tile mask: k > q
            int qi = q0 + lr;
            #pragma unroll
            for (int kb=0;kb<4;kb++)
                #pragma unroll
                for (int rr=0;rr<4;rr++)
                    if (kt*64 + kb*16 + lg*4 + rr > qi) sc[kb][rr] = -__builtin_inff();
        }

        // ---- max-free softmax: P = exp2(sc) straight to bf16 fragments ----
        bf16x8 pa[2];
        #pragma unroll
        for (int c=0;c<2;c++) {
            bf16x8 v;
            #pragma unroll
            for (int i=0;i<8;i++) v[i] = (bf16)exp2f(sc[c*2 + (i>>2)][i&3]);
            pa[c] = v;
        }

        // buf release: all 16 reads done, then barrier
        asm volatile("s_waitcnt lgkmcnt(0)" ::: "memory");
        __builtin_amdgcn_sched_barrier(0);
        __builtin_amdgcn_s_barrier();
        __builtin_amdgcn_sched_barrier(0);

        if (kt + 2 <= qt) stage(kt + 2);              // refill buf cur for tile kt+2

        // ---- O += P V;  l += P . 1 (registers only; covers the stage issue) ----
        __builtin_amdgcn_s_setprio(1);
        #pragma unroll
        for (int c=0;c<2;c++) {
            lacc = MFMA16(onesf, pa[c], lacc);
            #pragma unroll
            for (int n=0;n<4;n++)
                o[n] = MFMA16(vf[c][n], pa[c], o[n]);
        }
        __builtin_amdgcn_s_setprio(0);
    }

    // epilogue: normalize, write [b,s,h,d] as bf16x4 chunks
    float inv = 1.0f / lacc[0];
    int q = q0 + lr;
    #pragma unroll
    for (int n=0;n<4;n++) {
        bf16x4 ov;
        #pragma unroll
        for (int rr=0;rr<4;rr++) ov[rr] = (bf16)(o[n][rr] * inv);
        *(bf16x4*)&AO[((size_t)(b*NS + q)*NH + h)*HD + n*16 + lg*4] = ov;
    }
}

extern "C" void kernel_launch(void* const* d_in, const int* in_sizes, int n_in,
                              void* d_out, int out_size, void* d_ws, size_t ws_size,
                              hipStream_t stream) {
    const float* x     = (const float*)d_in[0];
    const float* w_in  = (const float*)d_in[1];
    const float* w_out = (const float*)d_in[2];
    float* out = (float*)d_out;

    char* p = (char*)d_ws;
    bf16* xb    = (bf16*)p; p += (size_t)BS*ND*2;          // 8 MB
    bf16* winb  = (bf16*)p; p += (size_t)D3*ND*2;          // 6 MB
    bf16* woutb = (bf16*)p; p += (size_t)ND*ND*2;          // 2 MB
    bf16* Qb    = (bf16*)p; p += (size_t)NB*NH*NS*HD*2;    // 8 MB
    bf16* Kb    = (bf16*)p; p += (size_t)NB*NH*NS*HD*2;    // 8 MB
    bf16* Vp    = (bf16*)p; p += (size_t)NB*NH*NS*HD*2;    // 8 MB  (V^T, k-permuted, [bh][d][s'])
    bf16* AO    = (bf16*)p; p += (size_t)BS*ND*2;          // 8 MB
    float2* csT = (float2*)p; p += (size_t)NS*32*8;        // 512 KB cos/sin interleaved

    prep<<<(CVTN + NS*32)/256, 256, 0, stream>>>(x, w_in, w_out, xb, winb, woutb, csT);
    gemm_qkv<<<512, 256, 0, stream>>>(xb, winb, Qb, Kb, Vp, csT);
    attn_fwd<<<NB*NH*NT, 256, 0, stream>>>(Qb, Kb, Vp, AO);
    gemm_out<<<512, 256, 0, stream>>>(AO, woutb, out, BS, ND, ND);
}